// Round 8
// baseline (220.958 us; speedup 1.0000x reference)
//
#include <hip/hip_runtime.h>
#include <math.h>

#define A_TOT  36864
#define N_IMG  32
#define M_GT   32
#define TOTAL_K 256
#define MAX_FG_K 128
#define NCHUNK 144          // chunks (256 anchors) per image
#define CPB    4            // chunks per k_finish block
#define BPF    36           // k_finish blocks per image
#define CAPF   1024         // boundary-candidate LDS capacity per class
#define RAW_NEG1 ((int)0xBF800000u)   // __float_as_int(-1.0f)
#define RAW_P07  ((int)0x3F333333u)   // __float_as_int(0.7f)
#define RAW_P03  ((int)0x3E99999Au)   // __float_as_int(0.3f)
typedef unsigned long long ull;
// IoU values live in {-1.0} ∪ [0,1]; signed-int compare of raw float bits ==
// float compare on that domain (no -0.0/NaN on the valid path).

__device__ __forceinline__ int bin_of(float r){
    int b = (int)(r * 1024.0f);
    return b > 1023 ? 1023 : (b < 0 ? 0 : b);
}

struct Pred { float x1,y1,x2,y2,area; int valid; };

__device__ __forceinline__ Pred mk_pred(float4 a, float4 d){
#pragma clang fp contract(off)
    Pred p;
    float w  = a.z - a.x + 1.0f;
    float h  = a.w - a.y + 1.0f;
    float cx = a.x + 0.5f*w;
    float cy = a.y + 0.5f*h;
    float pcx = d.x*w + cx;
    float pcy = d.y*h + cy;
    float pw = (float)exp((double)d.z) * w;
    float ph = (float)exp((double)d.w) * h;
    p.x1 = pcx - 0.5f*pw;
    p.y1 = pcy - 0.5f*ph;
    p.x2 = pcx + 0.5f*pw;
    p.y2 = pcy + 0.5f*ph;
    p.valid = (p.x1 >= 0.0f) && (p.y1 >= 0.0f) && (p.x2 < 1024.0f) && (p.y2 < 1024.0f);
    p.area  = (p.x2 - p.x1 + 1.0f) * (p.y2 - p.y1 + 1.0f);
    return p;
}

__device__ __forceinline__ float gt_area(float4 g){
#pragma clang fp contract(off)
    return (g.z - g.x + 1.0f) * (g.w - g.y + 1.0f);
}

__device__ __forceinline__ float iou_val(const Pred& p, float gx1, float gy1,
                                         float gx2, float gy2, float ga){
#pragma clang fp contract(off)
    float iw = fminf(p.x2,gx2) - fmaxf(p.x1,gx1) + 1.0f; iw = iw < 0.0f ? 0.0f : iw;
    float ih = fminf(p.y2,gy2) - fmaxf(p.y1,gy1) + 1.0f; ih = ih < 0.0f ? 0.0f : ih;
    float inter = iw * ih;
    float uni = (p.area + ga) - inter;
    float v = inter / uni;
    return p.valid ? v : -1.0f;
}

__device__ __forceinline__ void coeff_fn(float4 a, float4 g, float cf[4]){
#pragma clang fp contract(off)
    float aw = a.z - a.x + 1.0f, ah = a.w - a.y + 1.0f;
    float acx = a.x + 0.5f*aw,  acy = a.y + 0.5f*ah;
    float gw = g.z - g.x + 1.0f, gh = g.w - g.y + 1.0f;
    float gcx = g.x + 0.5f*gw,  gcy = g.y + 0.5f*gh;
    cf[0] = (gcx - acx) / aw;
    cf[1] = (gcy - acy) / ah;
    cf[2] = (float)log((double)(gw / aw));
    cf[3] = (float)log((double)(gh / ah));
}

// ---------- K1: IoU row in regs, chunk max, argmax, achiever mask.
// ---------- First 256 blocks also zero hist (65536 contiguous ints);
// ---------- safe: hist consumers run in later kernels. [unchanged from R7]
__global__ void k_main(const float* __restrict__ anchors, const float* __restrict__ gt,
                       const float* __restrict__ dl, const float* __restrict__ rs,
                       int* __restrict__ zbase, int* __restrict__ bmax,
                       int* __restrict__ flagsA, int* __restrict__ achA){
    int blk = blockIdx.x;
    int n = blk / NCHUNK, ch = blk % NCHUNK;
    int tid = threadIdx.x;
    if(blk < 256){ zbase[blk*256 + tid] = 0; }
    int a = ch*256 + tid;
    __shared__ float4 sgt[M_GT];
    __shared__ float  sga[M_GT];
    __shared__ int    sbm[M_GT];
    if(tid < M_GT){
        float4 g = ((const float4*)gt)[n*M_GT + tid];
        sgt[tid] = g; sga[tid] = gt_area(g); sbm[tid] = RAW_NEG1;
    }
    __syncthreads();
    float4 anc = ((const float4*)anchors)[a];
    float4 d   = ((const float4*)dl)[(long)n*A_TOT + a];
    Pred p = mk_pred(anc, d);
    int e[M_GT];
    int beste = (int)0x80000000u;    // INT_MIN < raw(-1.0)
    int bid = 0;
    int mm0 = tid & 31;
    #pragma unroll
    for(int j=0;j<M_GT;++j){
        int m = (mm0 + j) & 31;      // stagger: 2-way same-address LDS atomic (free)
        float4 g = sgt[m];
        float v = iou_val(p, g.x, g.y, g.z, g.w, sga[m]);
        int vi = __float_as_int(v);
        e[j] = vi;
        atomicMax(&sbm[m], vi);
        // rotated visit order => explicit (v desc, m asc) tie-break == first argmax
        if(vi > beste || (vi == beste && m < bid)){ beste = vi; bid = m; }
    }
    __syncthreads();
    unsigned ach = 0u;
    if(p.valid){
        #pragma unroll
        for(int j=0;j<M_GT;++j){
            int m = (mm0 + j) & 31;
            if(e[j] == sbm[m]) ach |= (1u << m);
        }
    }
    long ia = (long)n*A_TOT + a;
    int bin = bin_of(rs[ia]);
    // interim flags: bid[0:4] | thrfg<<5 | lt03<<6 | valid<<7 | bin<<8
    flagsA[ia] = bid | ((beste>=RAW_P07)?32:0) | ((beste<RAW_P03)?64:0)
               | (p.valid?128:0) | (bin<<8);
    achA[ia] = (int)ach;
    if(tid < M_GT) bmax[blk*M_GT + tid] = sbm[tid];
}

// ---------- K2: per-block redundant pgm from bmax (L2-hot), gmask via ballot,
// ---------- resolve fg/bg in-place, histogram via global atomics [unchanged] ---
__global__ void k_resolve(const int* __restrict__ bmax, const int* __restrict__ achA,
                          int* __restrict__ flagsA, int* __restrict__ hist){
    int blk = blockIdx.x;
    int n = blk / NCHUNK, ch = blk % NCHUNK;
    int tid = threadIdx.x;
    __shared__ int s_pgm[M_GT];
    __shared__ unsigned s_gmask;
    if(tid < M_GT) s_pgm[tid] = RAW_NEG1;
    __syncthreads();
    {   // 8 groups of 32 threads, 18 chunk-rows each; coalesced 128B reads
        int m = tid & 31, g = tid >> 5;
        const int* bm = bmax + n*NCHUNK*M_GT;
        int loc = RAW_NEG1;
        for(int c2 = g*18; c2 < (g+1)*18; ++c2) loc = max(loc, bm[c2*M_GT + m]);
        atomicMax(&s_pgm[m], loc);
    }
    __syncthreads();
    bool eq = (tid < M_GT) && (bmax[blk*M_GT + tid] == s_pgm[tid]);
    unsigned long long bb = __ballot(eq);
    if(tid == 0) s_gmask = (unsigned)(bb & 0xFFFFFFFFull);
    __syncthreads();
    unsigned gmask = s_gmask;
    long ia = (long)n*A_TOT + ch*256 + tid;
    int f = flagsA[ia];
    unsigned ach = (unsigned)achA[ia];
    int fg = ((f>>5)&1) | ((ach & gmask) != 0u ? 1 : 0);
    int bg = (!fg) & ((f>>6)&1) & ((f>>7)&1);
    int bin = (f>>8) & 1023;
    // final flags: bid[0:4] | fg<<5 | bg<<6 | bin<<7
    flagsA[ia] = (f & 31) | (fg<<5) | (bg<<6) | (bin<<7);
    if(fg | bg) atomicAdd(&hist[n*2048 + (fg?0:1024) + bin], 1);
}

// ---------- K3: quota + candidates + rank + scan + emit, all in one.
// ---------- 36 blocks/image; each streams the image's flagsA (L2-hot, 36x
// ---------- redundant = ~11 us VALU grid-wide) and emits its own 4 chunks. ---
__global__ __launch_bounds__(256)
void k_finish(const float* __restrict__ anchors, const float* __restrict__ gt,
              const float* __restrict__ rs, const int* __restrict__ flagsA,
              const int* __restrict__ hist, float* __restrict__ out){
    const int blk = blockIdx.x, tid = threadIdx.x;
    const int n = blk / BPF, cb = blk % BPF;
    const int wave = tid >> 6, lane = tid & 63;
    __shared__ int  s_scan[256];
    __shared__ int  s_q[4];                    // bsel0, take0, bsel1, take1
    __shared__ int  s_cc[NCHUNK][4];           // per-chunk per-wave sure counts
    __shared__ int  s_bk[NCHUNK];              // boundary-kept per chunk
    __shared__ int  s_chunkv[NCHUNK];
    __shared__ ull  s_key[2][CAPF];            // 16 KB candidate keys
    __shared__ unsigned s_kmap[A_TOT/32];      // 4.6 KB boundary-kept bitmap
    __shared__ int  s_cnt[2];
    __shared__ int  s_wc[CPB][4];
    __shared__ int  s_a0f;

    // ---- quota per class from global hist (L2-hot; proven k_bound code) ----
    int fgK = 0;
    for(int phase=0; phase<2; ++phase){
        int b0 = 1023 - 4*tid;                              // bins b0..b0-3 desc
        int4 h4 = *(const int4*)&hist[n*2048 + phase*1024 + b0 - 3];
        int part = h4.x + h4.y + h4.z + h4.w;
        s_scan[tid] = part;
        __syncthreads();
        for(int off=1; off<256; off<<=1){
            int add = (tid>=off) ? s_scan[tid-off] : 0;
            __syncthreads();
            s_scan[tid] += add;
            __syncthreads();
        }
        int total = s_scan[255];
        if(tid==0){ s_q[phase*2] = -1; s_q[phase*2+1] = 0; }
        __syncthreads();
        int quota = (phase==0) ? MAX_FG_K : (TOTAL_K - fgK);
        if(total > quota){
            int pre = s_scan[tid] - part, cum = pre;
            int hs4[4] = {h4.w, h4.z, h4.y, h4.x};          // descending bin order
            for(int j=0;j<4;++j){
                int hh = hs4[j];
                if(cum < quota && cum + hh >= quota){ s_q[phase*2] = b0-j; s_q[phase*2+1] = quota-cum; }
                cum += hh;
            }
        }
        __syncthreads();
        if(phase==0) fgK = (total < MAX_FG_K) ? total : MAX_FG_K;
    }
    const int bs0 = s_q[0], bs1 = s_q[2];
    const int tk0 = s_q[1], tk1 = s_q[3];

    // ---- init LDS state ----
    for(int i=tid;i<A_TOT/32;i+=256) s_kmap[i]=0u;
    for(int i=tid;i<NCHUNK;i+=256) s_bk[i]=0;
    if(tid<2) s_cnt[tid]=0;
    __syncthreads();

    // ---- stream whole image: sure counts per chunk + boundary candidates ----
    int fm0=0, fm1=0, fm2=0, fm3=0;            // my 4 chunks' flags
    const int myc = cb*CPB;
    for(int it=0; it<NCHUNK; ++it){
        int a = it*256 + tid;
        int f = flagsA[(long)n*A_TOT + a];
        int fg=(f>>5)&1, bg=(f>>6)&1, bin=(f>>7)&1023;
        int sure=0, c=-1;
        if(fg|bg){
            int bsel = fg ? bs0 : bs1;
            if(bin > bsel) sure = 1;           // keepAll encoded as bsel=-1
            else if(bin == bsel) c = fg ? 0 : 1;
        }
        if(c >= 0){
            int pos = atomicAdd(&s_cnt[c], 1);
            if(pos < CAPF){
                float r = rs[(long)n*A_TOT + a];
                // key: (r desc, index asc); r>=0 so raw bits order as uint
                s_key[c][pos] = (((ull)__float_as_uint(r))<<32) | (unsigned)(A_TOT - a);
            }
        }
        unsigned long long mk = __ballot(sure);
        if(lane==0) s_cc[it][wave] = __popcll(mk);
        if(it==myc) fm0=f; else if(it==myc+1) fm1=f;
        else if(it==myc+2) fm2=f; else if(it==myc+3) fm3=f;
    }
    __syncthreads();

    // ---- exact rank inside boundary bin (LDS O(c^2), c ~ 20-60) ----
    for(int c=0;c<2;++c){
        int cc = s_cnt[c]; if(cc > CAPF) cc = CAPF;
        int take = c ? tk1 : tk0;
        for(int i=tid; i<cc; i+=256){
            ull ki = s_key[c][i];
            int rank = 0;
            for(int j=0;j<cc;++j) rank += (s_key[c][j] > ki) ? 1 : 0;
            if(rank < take){
                int ai = A_TOT - (int)(ki & 0xffffffffu);
                atomicOr(&s_kmap[ai>>5], 1u<<(ai&31));
                atomicAdd(&s_bk[ai>>8], 1);
            }
        }
    }
    if(cb==0 && tid==0) s_a0f = fm0;           // anchor 0's flags (chunk 0, lane 0)
    __syncthreads();

    // ---- chunk totals + exclusive scan ----
    int v = (tid < NCHUNK) ? (s_cc[tid][0]+s_cc[tid][1]+s_cc[tid][2]+s_cc[tid][3]+s_bk[tid]) : 0;
    if(tid < NCHUNK) s_chunkv[tid] = v;
    s_scan[tid] = v;
    __syncthreads();
    for(int off=1; off<256; off<<=1){
        int add = (tid>=off) ? s_scan[tid-off] : 0;
        __syncthreads();
        s_scan[tid] += add;
        __syncthreads();
    }
    int total_kept = s_scan[255];

    // ---- emit my 4 chunks (ballot compaction, ascending anchor order) ----
    int fms[CPB] = {fm0, fm1, fm2, fm3};
    unsigned long long mks[CPB]; int kps[CPB];
    #pragma unroll
    for(int k=0;k<CPB;++k){
        int f = fms[k];
        int a = (myc+k)*256 + tid;
        int fg=(f>>5)&1, bg=(f>>6)&1, bin=(f>>7)&1023;
        int kept = 0;
        if(fg|bg){
            int bsel = fg ? bs0 : bs1;
            kept = (bin > bsel) || ((s_kmap[a>>5] >> (a&31)) & 1);
        }
        kps[k] = kept;
        mks[k] = __ballot(kept);
        if(lane==0) s_wc[k][wave] = __popcll(mks[k]);
    }
    __syncthreads();
    #pragma unroll
    for(int k=0;k<CPB;++k){
        if(kps[k]){
            int ch = myc + k;
            int a = ch*256 + tid;
            int f = fms[k];
            int base = s_scan[ch] - s_chunkv[ch];
            for(int w=0; w<wave; ++w) base += s_wc[k][w];
            int slot = base + __popcll(mks[k] & ((1ull<<lane)-1ull));
            if(slot < TOTAL_K){
                out[n*TOTAL_K + slot] = (float)a;
                out[(long)N_IMG*TOTAL_K + n*TOTAL_K + slot] = ((f>>5)&1) ? 1.0f : 0.0f;
                float4 aa = ((const float4*)anchors)[a];
                float4 gg = ((const float4*)gt)[n*M_GT + (f & 31)];
                float cf[4]; coeff_fn(aa, gg, cf);
                for(int kk=0;kk<4;++kk)
                    out[(long)2*N_IMG*TOTAL_K + ((long)n*TOTAL_K + slot)*4 + kk] = cf[kk];
            }
        }
    }
    // ---- defaults: slots >= total_kept behave like anchor 0 (cb==0 only;
    // ---- disjoint from emission slots, so no race) ----
    if(cb==0 && tid >= total_kept){
        int f0 = s_a0f;
        int fg0 = (f0>>5)&1, bin0 = (f0>>7)&1023;
        int kept0 = fg0 && ((bin0 > bs0) || (s_kmap[0] & 1u));
        float4 a0 = ((const float4*)anchors)[0];
        float4 g0 = ((const float4*)gt)[n*M_GT + (f0 & 31)];
        float cf0[4]; coeff_fn(a0, g0, cf0);
        out[n*TOTAL_K + tid] = 0.0f;
        out[(long)N_IMG*TOTAL_K + n*TOTAL_K + tid] = kept0 ? 1.0f : 0.0f;
        for(int kk=0;kk<4;++kk)
            out[(long)2*N_IMG*TOTAL_K + ((long)n*TOTAL_K + tid)*4 + kk] = cf0[kk];
    }
}

extern "C" void kernel_launch(void* const* d_in, const int* in_sizes, int n_in,
                              void* d_out, int out_size, void* d_ws, size_t ws_size,
                              hipStream_t stream){
    const float* anchors = (const float*)d_in[0];  // [36864,4]
    const float* gt      = (const float*)d_in[1];  // [32,32,4]
    const float* dl      = (const float*)d_in[2];  // [32,36864,4]
    const float* rs      = (const float*)d_in[3];  // [32,36864]
    float* out = (float*)d_out;                    // idx[32,256] | fg[32,256] | coeff[32,256,4]
    char* ws = (char*)d_ws;
    size_t off = 0;
    int* flagsA = (int*)(ws + off); off += (size_t)N_IMG*A_TOT*4;        // 4,718,592
    int* achA   = (int*)(ws + off); off += (size_t)N_IMG*A_TOT*4;        // 4,718,592
    int* bmax   = (int*)(ws + off); off += (size_t)N_IMG*NCHUNK*M_GT*4;  // 589,824
    int* hist   = (int*)(ws + off); off += (size_t)N_IMG*2048*4;         // 262,144

    hipLaunchKernelGGL(k_main,    dim3(N_IMG*NCHUNK), dim3(256), 0, stream,
                       anchors, gt, dl, rs, hist /*zbase*/, bmax, flagsA, achA);
    hipLaunchKernelGGL(k_resolve, dim3(N_IMG*NCHUNK), dim3(256), 0, stream,
                       bmax, achA, flagsA, hist);
    hipLaunchKernelGGL(k_finish,  dim3(N_IMG*BPF),    dim3(256), 0, stream,
                       anchors, gt, rs, flagsA, hist, out);
}

// Round 9
// 183.814 us; speedup vs baseline: 1.2021x; 1.2021x over previous
//
#include <hip/hip_runtime.h>
#include <math.h>

#define A_TOT  36864
#define N_IMG  32
#define M_GT   32
#define TOTAL_K 256
#define MAX_FG_K 128
#define NCHUNK 144          // chunks (256 anchors) per image
#define CAP    1024
#define KEEPB  (1<<17)
#define RAW_NEG1 ((int)0xBF800000u)   // __float_as_int(-1.0f)
#define RAW_P07  ((int)0x3F333333u)   // __float_as_int(0.7f)
#define RAW_P03  ((int)0x3E99999Au)   // __float_as_int(0.3f)
#define INT_MINV ((int)0x80000000u)
// IoU values live in {-1.0} ∪ [0,1]; signed-int compare of raw float bits ==
// float compare on that domain (no -0.0/NaN on the valid path).

__device__ __forceinline__ int bin_of(float r){
    int b = (int)(r * 1024.0f);
    return b > 1023 ? 1023 : (b < 0 ? 0 : b);
}

struct Pred { float x1,y1,x2,y2,area; int valid; };

__device__ __forceinline__ Pred mk_pred(float4 a, float4 d){
#pragma clang fp contract(off)
    Pred p;
    float w  = a.z - a.x + 1.0f;
    float h  = a.w - a.y + 1.0f;
    float cx = a.x + 0.5f*w;
    float cy = a.y + 0.5f*h;
    float pcx = d.x*w + cx;
    float pcy = d.y*h + cy;
    float pw = (float)exp((double)d.z) * w;
    float ph = (float)exp((double)d.w) * h;
    p.x1 = pcx - 0.5f*pw;
    p.y1 = pcy - 0.5f*ph;
    p.x2 = pcx + 0.5f*pw;
    p.y2 = pcy + 0.5f*ph;
    p.valid = (p.x1 >= 0.0f) && (p.y1 >= 0.0f) && (p.x2 < 1024.0f) && (p.y2 < 1024.0f);
    p.area  = (p.x2 - p.x1 + 1.0f) * (p.y2 - p.y1 + 1.0f);
    return p;
}

__device__ __forceinline__ float gt_area(float4 g){
#pragma clang fp contract(off)
    return (g.z - g.x + 1.0f) * (g.w - g.y + 1.0f);
}

__device__ __forceinline__ float iou_val(const Pred& p, float gx1, float gy1,
                                         float gx2, float gy2, float ga){
#pragma clang fp contract(off)
    float iw = fminf(p.x2,gx2) - fmaxf(p.x1,gx1) + 1.0f; iw = iw < 0.0f ? 0.0f : iw;
    float ih = fminf(p.y2,gy2) - fmaxf(p.y1,gy1) + 1.0f; ih = ih < 0.0f ? 0.0f : ih;
    float inter = iw * ih;
    float uni = (p.area + ga) - inter;
    float v = inter / uni;
    return p.valid ? v : -1.0f;
}

__device__ __forceinline__ void coeff_fn(float4 a, float4 g, float cf[4]){
#pragma clang fp contract(off)
    float aw = a.z - a.x + 1.0f, ah = a.w - a.y + 1.0f;
    float acx = a.x + 0.5f*aw,  acy = a.y + 0.5f*ah;
    float gw = g.z - g.x + 1.0f, gh = g.w - g.y + 1.0f;
    float gcx = g.x + 0.5f*gw,  gcy = g.y + 0.5f*gh;
    cf[0] = (gcx - acx) / aw;
    cf[1] = (gcy - acy) / ah;
    cf[2] = (float)log((double)(gw / aw));
    cf[3] = (float)log((double)(gh / ah));
}

// ascending-m first-argmax of anchor-vs-all-gt IoU (reference semantics)
__device__ __forceinline__ int argmax_gt(const float* anchors, const float* gt,
                                         const float* dl, int n, int a){
    float4 anc = ((const float4*)anchors)[a];
    float4 d   = ((const float4*)dl)[(long)n*A_TOT + a];
    Pred p = mk_pred(anc, d);
    int be = INT_MINV, bd = 0;
    for(int m=0;m<M_GT;++m){
        float4 g = ((const float4*)gt)[n*M_GT + m];
        float v = iou_val(p, g.x, g.y, g.z, g.w, gt_area(g));
        int vi = __float_as_int(v);
        if(vi > be){ be = vi; bd = m; }
    }
    return bd;
}

// ---------- K1: slim heavy pass: IoU row, chunk max, beste thresholds.
// ---------- No e[] array, no ach pass, no argmax. First 257 blocks zero
// ---------- hist|candcnt (65600 contiguous ints; consumers run later). ----
__global__ void k_main(const float* __restrict__ anchors, const float* __restrict__ gt,
                       const float* __restrict__ dl, const float* __restrict__ rs,
                       int* __restrict__ zbase, int* __restrict__ bmax,
                       int* __restrict__ flagsA){
    int blk = blockIdx.x;
    int n = blk / NCHUNK, ch = blk % NCHUNK;
    int tid = threadIdx.x;
    if(blk < 257){ int z = blk*256 + tid; if(z < 65600) zbase[z] = 0; }
    int a = ch*256 + tid;
    __shared__ float4 sgt[M_GT];
    __shared__ float  sga[M_GT];
    __shared__ int    sbm[M_GT];
    if(tid < M_GT){
        float4 g = ((const float4*)gt)[n*M_GT + tid];
        sgt[tid] = g; sga[tid] = gt_area(g); sbm[tid] = RAW_NEG1;
    }
    __syncthreads();
    float4 anc = ((const float4*)anchors)[a];
    float4 d   = ((const float4*)dl)[(long)n*A_TOT + a];
    Pred p = mk_pred(anc, d);
    int beste = INT_MINV;
    int mm0 = tid & 31;
    #pragma unroll
    for(int j=0;j<M_GT;++j){
        int m = (mm0 + j) & 31;      // stagger: 2-way same-address LDS atomic (free)
        float4 g = sgt[m];
        float v = iou_val(p, g.x, g.y, g.z, g.w, sga[m]);
        int vi = __float_as_int(v);
        atomicMax(&sbm[m], vi);
        beste = max(beste, vi);      // thresholds only; argmax recomputed sparsely
    }
    __syncthreads();
    long ia = (long)n*A_TOT + a;
    int bin = bin_of(rs[ia]);
    // interim flags: thrfg<<5 | lt03<<6 | valid<<7 | bin<<8
    flagsA[ia] = ((beste>=RAW_P07)?32:0) | ((beste<RAW_P03)?64:0)
               | (p.valid?128:0) | (bin<<8);
    if(tid < M_GT) bmax[blk*M_GT + tid] = sbm[tid];
}

// ---------- K2: per-block redundant pgm from bmax (L2-hot), gmask via ballot,
// ---------- sparse abox recompute (only gmask!=0 blocks), finalize labels ----
__global__ void k_resolve(const float* __restrict__ anchors, const float* __restrict__ gt,
                          const float* __restrict__ dl, const int* __restrict__ bmax,
                          int* __restrict__ flagsA, int* __restrict__ hist){
    int blk = blockIdx.x;
    int n = blk / NCHUNK, ch = blk % NCHUNK;
    int tid = threadIdx.x;
    __shared__ int s_pgm[M_GT];
    __shared__ unsigned s_gmask;
    if(tid < M_GT) s_pgm[tid] = RAW_NEG1;
    __syncthreads();
    {   // 8 groups of 32 threads, 18 chunk-rows each; coalesced 128B reads
        int m = tid & 31, g = tid >> 5;
        const int* bm = bmax + n*NCHUNK*M_GT;
        int loc = RAW_NEG1;
        for(int c2 = g*18; c2 < (g+1)*18; ++c2) loc = max(loc, bm[c2*M_GT + m]);
        atomicMax(&s_pgm[m], loc);
    }
    __syncthreads();
    bool eq = (tid < M_GT) && (bmax[blk*M_GT + tid] == s_pgm[tid]);
    unsigned long long bb = __ballot(eq);
    if(tid == 0) s_gmask = (unsigned)(bb & 0xFFFFFFFFull);
    __syncthreads();
    unsigned gmask = s_gmask;
    int a = ch*256 + tid;
    long ia = (long)n*A_TOT + a;
    int f = flagsA[ia];
    int abox = 0;
    if(gmask){   // block-uniform branch; ~1% of blocks contain potential achievers
        float4 anc = ((const float4*)anchors)[a];
        float4 d   = ((const float4*)dl)[ia];
        Pred p = mk_pred(anc, d);
        if(p.valid){
            unsigned gm = gmask;
            while(gm){
                int m = __ffs(gm) - 1; gm &= gm - 1;
                float4 g = ((const float4*)gt)[n*M_GT + m];
                float v = iou_val(p, g.x, g.y, g.z, g.w, gt_area(g));
                if(__float_as_int(v) == s_pgm[m]) abox = 1;
            }
        }
    }
    int fg = ((f>>5)&1) | abox;
    int bg = (!fg) & ((f>>6)&1) & ((f>>7)&1);
    int bin = (f>>8) & 1023;
    // final flags: fg<<5 | bg<<6 | bin<<7   (bit 17 = KEEPB, free)
    flagsA[ia] = (fg<<5) | (bg<<6) | (bin<<7);
    if(fg | bg) atomicAdd(&hist[n*2048 + (fg?0:1024) + bin], 1);
}

// ---------- K3: inline per-block quota (redundant, hist is L2-hot) +
// ---------- sure-keeps, boundary candidates, chunk counts; ch==0 publishes q ---
__global__ void k_bound(const int* __restrict__ flagsA, const float* __restrict__ rs,
                        const int* __restrict__ hist, int* __restrict__ q,
                        unsigned long long* __restrict__ cand, int* __restrict__ candcnt,
                        int* __restrict__ chunkcnt){
    int blk = blockIdx.x, tid = threadIdx.x;
    int n = blk / NCHUNK, ch = blk % NCHUNK;
    int wave = tid >> 6, lane = tid & 63;
    __shared__ int s_scan[256];
    __shared__ int s_q[4];
    __shared__ int s_wc[4];
    int fgK = 0;
    for(int phase=0; phase<2; ++phase){
        int b0 = 1023 - 4*tid;                              // bins b0..b0-3 desc
        int4 h4 = *(const int4*)&hist[n*2048 + phase*1024 + b0 - 3];
        int part = h4.x + h4.y + h4.z + h4.w;
        s_scan[tid] = part;
        __syncthreads();
        for(int off=1; off<256; off<<=1){
            int add = (tid>=off) ? s_scan[tid-off] : 0;
            __syncthreads();
            s_scan[tid] += add;
            __syncthreads();
        }
        int total = s_scan[255];
        if(tid==0){ s_q[phase*2] = -1; s_q[phase*2+1] = 0; }
        __syncthreads();
        int quota = (phase==0) ? MAX_FG_K : (TOTAL_K - fgK);
        if(total > quota){
            int pre = s_scan[tid] - part, cum = pre;
            int hs4[4] = {h4.w, h4.z, h4.y, h4.x};          // descending bin order
            for(int j=0;j<4;++j){
                int hh = hs4[j];
                if(cum < quota && cum + hh >= quota){ s_q[phase*2] = b0-j; s_q[phase*2+1] = quota-cum; }
                cum += hh;
            }
        }
        __syncthreads();
        if(phase==0) fgK = (total < MAX_FG_K) ? total : MAX_FG_K;
    }
    int bs0 = s_q[0], bs1 = s_q[2];
    if(ch==0 && tid<4) q[n*4 + tid] = s_q[tid];
    int a = ch*256 + tid;
    long ia = (long)n*A_TOT + a;
    int f = flagsA[ia];
    int fg = (f>>5)&1, bg = (f>>6)&1, bin = (f>>7)&1023;
    int sure = 0;
    if(fg | bg){
        int c = fg ? 0 : 1;
        int bsel = fg ? bs0 : bs1;
        if(bin > bsel) sure = 1;                 // keepAll encoded as bsel=-1
        else if(bin == bsel){
            int pos = atomicAdd(&candcnt[n*2+c], 1);
            if(pos < CAP){
                // key: (r desc, index asc); r>=0 so raw bits order as uint
                cand[(n*2+c)*CAP + pos] =
                    (((unsigned long long)__float_as_uint(rs[ia]))<<32) | (unsigned)(A_TOT - a);
            }
        }
    }
    unsigned long long mk = __ballot(sure);
    if(lane==0) s_wc[wave] = __popcll(mk);
    __syncthreads();
    if(tid==0) chunkcnt[n*NCHUNK + ch] = s_wc[0]+s_wc[1]+s_wc[2]+s_wc[3];
}

// ---------- K4: rank boundary candidates (LDS O(c^2)), chunk-base scan, defaults ---
__global__ void k_rank(const float* __restrict__ anchors, const float* __restrict__ gt,
                       const float* __restrict__ dl, int* __restrict__ flagsA,
                       const int* __restrict__ q, const int* __restrict__ candcnt,
                       const unsigned long long* __restrict__ cand,
                       const int* __restrict__ chunkcnt, int* __restrict__ cbase,
                       float* __restrict__ out){
    int n = blockIdx.x, tid = threadIdx.x;
    __shared__ unsigned long long s_ckey[CAP];   // 8 KB
    __shared__ int s_chunk[NCHUNK];
    __shared__ int s_scan[256];
    __shared__ int s_i0[M_GT];
    __shared__ int s_k0b;
    if(tid < NCHUNK) s_chunk[tid] = chunkcnt[n*NCHUNK + tid];
    if(tid==0) s_k0b = 0;
    int bs0 = q[n*4+0];
    int tk[2] = { q[n*4+1], q[n*4+3] };
    int m0 = flagsA[(long)n*A_TOT];              // read before any KEEPB writes
    // anchor-0 IoU row (for default gt_id), parallel across 32 threads
    if(tid < M_GT){
        float4 anc = ((const float4*)anchors)[0];
        float4 d   = ((const float4*)dl)[(long)n*A_TOT];
        Pred p = mk_pred(anc, d);
        float4 g = ((const float4*)gt)[n*M_GT + tid];
        s_i0[tid] = __float_as_int(iou_val(p, g.x, g.y, g.z, g.w, gt_area(g)));
    }
    __syncthreads();
    for(int c=0;c<2;++c){
        int cc = candcnt[n*2+c]; if(cc > CAP) cc = CAP;
        int take = tk[c];
        for(int i=tid; i<cc; i+=256) s_ckey[i] = cand[(n*2+c)*CAP + i];
        __syncthreads();
        for(int i=tid; i<cc; i+=256){
            unsigned long long ki = s_ckey[i];
            int rank = 0;
            for(int j=0;j<cc;++j) rank += (s_ckey[j] > ki) ? 1 : 0;
            if(rank < take){
                int ai = A_TOT - (int)(ki & 0xffffffffu);
                flagsA[(long)n*A_TOT + ai] |= KEEPB;   // one writer per anchor
                atomicAdd(&s_chunk[ai>>8], 1);
                if(ai==0 && c==0) s_k0b = 1;
            }
        }
        __syncthreads();
    }
    int v = (tid < NCHUNK) ? s_chunk[tid] : 0;
    s_scan[tid] = v;
    __syncthreads();
    for(int off=1; off<256; off<<=1){
        int add = (tid>=off) ? s_scan[tid-off] : 0;
        __syncthreads();
        s_scan[tid] += add;
        __syncthreads();
    }
    if(tid < NCHUNK) cbase[n*NCHUNK + tid] = s_scan[tid] - v;
    // defaults: padding slots behave like anchor 0 (reference zero-init scatter)
    int be = INT_MINV, bid0 = 0;
    for(int m=0;m<M_GT;++m){ int e = s_i0[m]; if(e > be){ be = e; bid0 = m; } }
    int fg0 = (m0>>5)&1, bin0 = (m0>>7)&1023;
    float fgdef = (fg0 && ((bin0 > bs0) || s_k0b)) ? 1.0f : 0.0f;
    float4 a0 = ((const float4*)anchors)[0];
    float4 g0 = ((const float4*)gt)[n*M_GT + bid0];
    float cf0[4]; coeff_fn(a0, g0, cf0);
    out[n*TOTAL_K + tid] = 0.0f;
    out[(long)N_IMG*TOTAL_K + n*TOTAL_K + tid] = fgdef;
    for(int k=0;k<4;++k)
        out[(long)2*N_IMG*TOTAL_K + ((long)n*TOTAL_K + tid)*4 + k] = cf0[k];
}

// ---------- K5: chunk-parallel ballot compaction + emit (argmax recomputed
// ---------- only on kept lanes, ~256/image) ----------
__global__ void k_out(const float* __restrict__ anchors, const float* __restrict__ gt,
                      const float* __restrict__ dl, const int* __restrict__ flagsA,
                      const int* __restrict__ q, const int* __restrict__ cbase,
                      float* __restrict__ out){
    int blk = blockIdx.x, tid = threadIdx.x;
    int n = blk / NCHUNK, ch = blk % NCHUNK;
    int wave = tid >> 6, lane = tid & 63;
    int a = ch*256 + tid;
    int bs0 = q[n*4+0], bs1 = q[n*4+2];
    int f = flagsA[(long)n*A_TOT + a];
    int fg = (f>>5)&1, bg = (f>>6)&1, bin = (f>>7)&1023;
    int kept = 0;
    if(fg)      kept = (bin > bs0) || ((f & KEEPB) != 0);
    else if(bg) kept = (bin > bs1) || ((f & KEEPB) != 0);
    __shared__ int s_wc[4];
    unsigned long long mk = __ballot(kept);
    if(lane==0) s_wc[wave] = __popcll(mk);
    __syncthreads();
    if(kept){
        int base = cbase[n*NCHUNK + ch];
        for(int w=0; w<wave; ++w) base += s_wc[w];
        int slot = base + __popcll(mk & ((1ull<<lane)-1ull));
        if(slot < TOTAL_K){
            int bid = argmax_gt(anchors, gt, dl, n, a);
            out[n*TOTAL_K + slot] = (float)a;
            out[(long)N_IMG*TOTAL_K + n*TOTAL_K + slot] = fg ? 1.0f : 0.0f;
            float4 aa = ((const float4*)anchors)[a];
            float4 gg = ((const float4*)gt)[n*M_GT + bid];
            float cf[4]; coeff_fn(aa, gg, cf);
            for(int k=0;k<4;++k)
                out[(long)2*N_IMG*TOTAL_K + ((long)n*TOTAL_K + slot)*4 + k] = cf[k];
        }
    }
}

extern "C" void kernel_launch(void* const* d_in, const int* in_sizes, int n_in,
                              void* d_out, int out_size, void* d_ws, size_t ws_size,
                              hipStream_t stream){
    const float* anchors = (const float*)d_in[0];  // [36864,4]
    const float* gt      = (const float*)d_in[1];  // [32,32,4]
    const float* dl      = (const float*)d_in[2];  // [32,36864,4]
    const float* rs      = (const float*)d_in[3];  // [32,36864]
    float* out = (float*)d_out;                    // idx[32,256] | fg[32,256] | coeff[32,256,4]
    char* ws = (char*)d_ws;
    size_t off = 0;
    int* flagsA   = (int*)(ws + off); off += (size_t)N_IMG*A_TOT*4;        // 4,718,592
    int* bmax     = (int*)(ws + off); off += (size_t)N_IMG*NCHUNK*M_GT*4;  // 589,824
    int* hist     = (int*)(ws + off); off += (size_t)N_IMG*2048*4;         // 262,144
    int* candcnt  = (int*)(ws + off); off += 256;                          // 64 ints, zeroed w/ hist
    int* q        = (int*)(ws + off); off += 512;
    unsigned long long* cand = (unsigned long long*)(ws + off); off += (size_t)N_IMG*2*CAP*8;
    int* chunkcnt = (int*)(ws + off); off += (size_t)N_IMG*NCHUNK*4;
    int* cbase    = (int*)(ws + off); off += (size_t)N_IMG*NCHUNK*4;

    hipLaunchKernelGGL(k_main,    dim3(N_IMG*NCHUNK), dim3(256), 0, stream,
                       anchors, gt, dl, rs, hist /*zbase: hist|candcnt contiguous*/, bmax, flagsA);
    hipLaunchKernelGGL(k_resolve, dim3(N_IMG*NCHUNK), dim3(256), 0, stream,
                       anchors, gt, dl, bmax, flagsA, hist);
    hipLaunchKernelGGL(k_bound,   dim3(N_IMG*NCHUNK), dim3(256), 0, stream,
                       flagsA, rs, hist, q, cand, candcnt, chunkcnt);
    hipLaunchKernelGGL(k_rank,    dim3(N_IMG),        dim3(256), 0, stream,
                       anchors, gt, dl, flagsA, q, candcnt, cand, chunkcnt, cbase, out);
    hipLaunchKernelGGL(k_out,     dim3(N_IMG*NCHUNK), dim3(256), 0, stream,
                       anchors, gt, dl, flagsA, q, cbase, out);
}

// Round 10
// 144.181 us; speedup vs baseline: 1.5325x; 1.2749x over previous
//
#include <hip/hip_runtime.h>
#include <math.h>

#define A_TOT  36864
#define N_IMG  32
#define M_GT   32
#define TOTAL_K 256
#define MAX_FG_K 128
#define NCHUNK 144          // chunks (256 anchors) per image
#define CAP    1024
#define KEEPB  (1<<17)
#define FGB    32
#define BGB    64
#define RAW_NEG1 ((int)0xBF800000u)   // __float_as_int(-1.0f)
#define RAW_P07  ((int)0x3F333333u)   // __float_as_int(0.7f)
#define RAW_P03  ((int)0x3E99999Au)   // __float_as_int(0.3f)
#define INT_MINV ((int)0x80000000u)
// IoU values live in {-1.0} ∪ [0,1]; signed-int compare of raw float bits ==
// float compare on that domain (no -0.0/NaN on the valid path).
// flags layout: bid[0:4] | fg<<5 | bg<<6 | bin<<7 (10b) | KEEPB<<17
// (bg bit may stay set on fg-promoted anchors; consumers use bg & !fg)

__device__ __forceinline__ int bin_of(float r){
    int b = (int)(r * 1024.0f);
    return b > 1023 ? 1023 : (b < 0 ? 0 : b);
}

struct Pred { float x1,y1,x2,y2,area; int valid; };

__device__ __forceinline__ Pred mk_pred(float4 a, float4 d){
#pragma clang fp contract(off)
    Pred p;
    float w  = a.z - a.x + 1.0f;
    float h  = a.w - a.y + 1.0f;
    float cx = a.x + 0.5f*w;
    float cy = a.y + 0.5f*h;
    float pcx = d.x*w + cx;
    float pcy = d.y*h + cy;
    float pw = (float)exp((double)d.z) * w;
    float ph = (float)exp((double)d.w) * h;
    p.x1 = pcx - 0.5f*pw;
    p.y1 = pcy - 0.5f*ph;
    p.x2 = pcx + 0.5f*pw;
    p.y2 = pcy + 0.5f*ph;
    p.valid = (p.x1 >= 0.0f) && (p.y1 >= 0.0f) && (p.x2 < 1024.0f) && (p.y2 < 1024.0f);
    p.area  = (p.x2 - p.x1 + 1.0f) * (p.y2 - p.y1 + 1.0f);
    return p;
}

__device__ __forceinline__ float gt_area(float4 g){
#pragma clang fp contract(off)
    return (g.z - g.x + 1.0f) * (g.w - g.y + 1.0f);
}

__device__ __forceinline__ float iou_val(const Pred& p, float gx1, float gy1,
                                         float gx2, float gy2, float ga){
#pragma clang fp contract(off)
    float iw = fminf(p.x2,gx2) - fmaxf(p.x1,gx1) + 1.0f; iw = iw < 0.0f ? 0.0f : iw;
    float ih = fminf(p.y2,gy2) - fmaxf(p.y1,gy1) + 1.0f; ih = ih < 0.0f ? 0.0f : ih;
    float inter = iw * ih;
    float uni = (p.area + ga) - inter;
    float v = inter / uni;
    return p.valid ? v : -1.0f;
}

__device__ __forceinline__ void coeff_fn(float4 a, float4 g, float cf[4]){
#pragma clang fp contract(off)
    float aw = a.z - a.x + 1.0f, ah = a.w - a.y + 1.0f;
    float acx = a.x + 0.5f*aw,  acy = a.y + 0.5f*ah;
    float gw = g.z - g.x + 1.0f, gh = g.w - g.y + 1.0f;
    float gcx = g.x + 0.5f*gw,  gcy = g.y + 0.5f*gh;
    cf[0] = (gcx - acx) / aw;
    cf[1] = (gcy - acy) / ah;
    cf[2] = (float)log((double)(gw / aw));
    cf[3] = (float)log((double)(gh / ah));
}

// ---------- K1: heavy pass. Final flags (fg=thrfg), hist atomics, bmax,
// ---------- pgm via atomicMax straight over 0xAA poison (poison < raw(-1)). ---
__global__ void k_main(const float* __restrict__ anchors, const float* __restrict__ gt,
                       const float* __restrict__ dl, const float* __restrict__ rs,
                       int* __restrict__ bmax, int* __restrict__ flagsA,
                       int* __restrict__ pgm, int* __restrict__ hist){
    int blk = blockIdx.x;
    int n = blk / NCHUNK, ch = blk % NCHUNK;
    int tid = threadIdx.x;
    int a = ch*256 + tid;
    __shared__ float4 sgt[M_GT];
    __shared__ float  sga[M_GT];
    __shared__ int    sbm[M_GT];
    if(tid < M_GT){
        float4 g = ((const float4*)gt)[n*M_GT + tid];
        sgt[tid] = g; sga[tid] = gt_area(g); sbm[tid] = RAW_NEG1;
    }
    __syncthreads();
    float4 anc = ((const float4*)anchors)[a];
    float4 d   = ((const float4*)dl)[(long)n*A_TOT + a];
    Pred p = mk_pred(anc, d);
    int beste = INT_MINV, bid = 0;
    int mm0 = tid & 31;
    #pragma unroll
    for(int j=0;j<M_GT;++j){
        int m = (mm0 + j) & 31;      // stagger: 2-way same-address LDS atomic (free)
        float4 g = sgt[m];
        float v = iou_val(p, g.x, g.y, g.z, g.w, sga[m]);
        int vi = __float_as_int(v);
        atomicMax(&sbm[m], vi);
        // rotated visit order => explicit (v desc, m asc) tie-break == first argmax
        if(vi > beste || (vi == beste && m < bid)){ beste = vi; bid = m; }
    }
    __syncthreads();
    long ia = (long)n*A_TOT + a;
    int bin = bin_of(rs[ia]);
    int thrfg = (beste >= RAW_P07) ? 1 : 0;
    int bg0 = (!thrfg) & (beste < RAW_P03 ? 1 : 0) & p.valid;
    flagsA[ia] = bid | (thrfg<<5) | (bg0<<6) | (bin<<7);
    if(thrfg | bg0) atomicAdd(&hist[n*2048 + (thrfg?0:1024) + bin], 1);
    if(tid < M_GT){
        bmax[blk*M_GT + tid] = sbm[tid];
        atomicMax(&pgm[n*M_GT + tid], sbm[tid]);   // poison 0xAAAAAAAA < raw(-1): no init needed
    }
}

// ---------- K2: sparse abox fix. One block per (image, gt); only blocks with
// ---------- bmax==pgm contain achievers (pgm>=0 => achiever valid). Exactly-
// ---------- once hist repair via atomicOr(fg) old-value. ----------
__global__ void k_fix(const float* __restrict__ anchors, const float* __restrict__ gt,
                      const float* __restrict__ dl, const int* __restrict__ bmax,
                      const int* __restrict__ pgm, int* __restrict__ flagsA,
                      int* __restrict__ hist){
    int n = blockIdx.x >> 5, m = blockIdx.x & 31;
    int tid = threadIdx.x;
    int target = pgm[n*M_GT + m];
    float4 g = ((const float4*)gt)[n*M_GT + m];
    float ga = gt_area(g);
    __shared__ int s_hits[NCHUNK];
    __shared__ int s_nh;
    if(tid==0) s_nh = 0;
    __syncthreads();
    if(tid < NCHUNK && bmax[(n*NCHUNK + tid)*M_GT + m] == target){
        int pos = atomicAdd(&s_nh, 1);
        s_hits[pos] = tid;
    }
    __syncthreads();
    int nh = s_nh;
    for(int h=0; h<nh; ++h){
        int ch = s_hits[h];
        int a = ch*256 + tid;
        long ia = (long)n*A_TOT + a;
        float4 anc = ((const float4*)anchors)[a];
        float4 d   = ((const float4*)dl)[ia];
        Pred p = mk_pred(anc, d);
        float v = iou_val(p, g.x, g.y, g.z, g.w, ga);
        if(p.valid && __float_as_int(v) == target){
            int old = atomicOr(&flagsA[ia], FGB);
            if(!(old & FGB)){                 // fg transition: repair histogram
                int bin = (old >> 7) & 1023;
                atomicAdd(&hist[n*2048 + bin], 1);
                if(old & BGB) atomicSub(&hist[n*2048 + 1024 + bin], 1);
            }
        }
    }
}

// ---------- K3: inline per-block quota (redundant, hist is L2-hot) +
// ---------- sure-keeps, boundary candidates, chunk counts; ch==0 publishes q ---
__global__ void k_bound(const int* __restrict__ flagsA, const float* __restrict__ rs,
                        const int* __restrict__ hist, int* __restrict__ q,
                        unsigned long long* __restrict__ cand, int* __restrict__ candcnt,
                        int* __restrict__ chunkcnt){
    int blk = blockIdx.x, tid = threadIdx.x;
    int n = blk / NCHUNK, ch = blk % NCHUNK;
    int wave = tid >> 6, lane = tid & 63;
    __shared__ int s_scan[256];
    __shared__ int s_q[4];
    __shared__ int s_wc[4];
    int fgK = 0;
    for(int phase=0; phase<2; ++phase){
        int b0 = 1023 - 4*tid;                              // bins b0..b0-3 desc
        int4 h4 = *(const int4*)&hist[n*2048 + phase*1024 + b0 - 3];
        int part = h4.x + h4.y + h4.z + h4.w;
        s_scan[tid] = part;
        __syncthreads();
        for(int off=1; off<256; off<<=1){
            int add = (tid>=off) ? s_scan[tid-off] : 0;
            __syncthreads();
            s_scan[tid] += add;
            __syncthreads();
        }
        int total = s_scan[255];
        if(tid==0){ s_q[phase*2] = -1; s_q[phase*2+1] = 0; }
        __syncthreads();
        int quota = (phase==0) ? MAX_FG_K : (TOTAL_K - fgK);
        if(total > quota){
            int pre = s_scan[tid] - part, cum = pre;
            int hs4[4] = {h4.w, h4.z, h4.y, h4.x};          // descending bin order
            for(int j=0;j<4;++j){
                int hh = hs4[j];
                if(cum < quota && cum + hh >= quota){ s_q[phase*2] = b0-j; s_q[phase*2+1] = quota-cum; }
                cum += hh;
            }
        }
        __syncthreads();
        if(phase==0) fgK = (total < MAX_FG_K) ? total : MAX_FG_K;
    }
    int bs0 = s_q[0], bs1 = s_q[2];
    if(ch==0 && tid<4) q[n*4 + tid] = s_q[tid];
    int a = ch*256 + tid;
    long ia = (long)n*A_TOT + a;
    int f = flagsA[ia];
    int fg = (f>>5)&1;
    int bg = ((f>>6)&1) & !fg;
    int bin = (f>>7)&1023;
    int sure = 0;
    if(fg | bg){
        int c = fg ? 0 : 1;
        int bsel = fg ? bs0 : bs1;
        if(bin > bsel) sure = 1;                 // keepAll encoded as bsel=-1
        else if(bin == bsel){
            int pos = atomicAdd(&candcnt[n*2+c], 1);
            if(pos < CAP){
                // key: (r desc, index asc); r>=0 so raw bits order as uint
                cand[(n*2+c)*CAP + pos] =
                    (((unsigned long long)__float_as_uint(rs[ia]))<<32) | (unsigned)(A_TOT - a);
            }
        }
    }
    unsigned long long mk = __ballot(sure);
    if(lane==0) s_wc[wave] = __popcll(mk);
    __syncthreads();
    if(tid==0) chunkcnt[n*NCHUNK + ch] = s_wc[0]+s_wc[1]+s_wc[2]+s_wc[3];
}

// ---------- K4: rank boundary candidates (LDS O(c^2)), chunk-base scan, defaults ---
__global__ void k_rank(const float* __restrict__ anchors, const float* __restrict__ gt,
                       int* __restrict__ flagsA, const int* __restrict__ q,
                       const int* __restrict__ candcnt,
                       const unsigned long long* __restrict__ cand,
                       const int* __restrict__ chunkcnt, int* __restrict__ cbase,
                       float* __restrict__ out){
    int n = blockIdx.x, tid = threadIdx.x;
    __shared__ unsigned long long s_ckey[CAP];   // 8 KB
    __shared__ int s_chunk[NCHUNK];
    __shared__ int s_scan[256];
    __shared__ int s_k0b;
    if(tid < NCHUNK) s_chunk[tid] = chunkcnt[n*NCHUNK + tid];
    if(tid==0) s_k0b = 0;
    int bs0 = q[n*4+0];
    int tk[2] = { q[n*4+1], q[n*4+3] };
    int m0 = flagsA[(long)n*A_TOT];              // read before any KEEPB writes
    __syncthreads();
    for(int c=0;c<2;++c){
        int cc = candcnt[n*2+c]; if(cc > CAP) cc = CAP;
        int take = tk[c];
        for(int i=tid; i<cc; i+=256) s_ckey[i] = cand[(n*2+c)*CAP + i];
        __syncthreads();
        for(int i=tid; i<cc; i+=256){
            unsigned long long ki = s_ckey[i];
            int rank = 0;
            for(int j=0;j<cc;++j) rank += (s_ckey[j] > ki) ? 1 : 0;
            if(rank < take){
                int ai = A_TOT - (int)(ki & 0xffffffffu);
                atomicOr(&flagsA[(long)n*A_TOT + ai], KEEPB);
                atomicAdd(&s_chunk[ai>>8], 1);
                if(ai==0 && c==0) s_k0b = 1;
            }
        }
        __syncthreads();
    }
    int v = (tid < NCHUNK) ? s_chunk[tid] : 0;
    s_scan[tid] = v;
    __syncthreads();
    for(int off=1; off<256; off<<=1){
        int add = (tid>=off) ? s_scan[tid-off] : 0;
        __syncthreads();
        s_scan[tid] += add;
        __syncthreads();
    }
    if(tid < NCHUNK) cbase[n*NCHUNK + tid] = s_scan[tid] - v;
    // defaults: padding slots behave like anchor 0 (reference zero-init scatter)
    int fg0 = (m0>>5)&1, bin0 = (m0>>7)&1023;
    float fgdef = (fg0 && ((bin0 > bs0) || s_k0b)) ? 1.0f : 0.0f;
    float4 a0 = ((const float4*)anchors)[0];
    float4 g0 = ((const float4*)gt)[n*M_GT + (m0 & 31)];
    float cf0[4]; coeff_fn(a0, g0, cf0);
    out[n*TOTAL_K + tid] = 0.0f;
    out[(long)N_IMG*TOTAL_K + n*TOTAL_K + tid] = fgdef;
    for(int k=0;k<4;++k)
        out[(long)2*N_IMG*TOTAL_K + ((long)n*TOTAL_K + tid)*4 + k] = cf0[k];
}

// ---------- K5: chunk-parallel ballot compaction + emit (bid from flags) ----
__global__ void k_out(const float* __restrict__ anchors, const float* __restrict__ gt,
                      const int* __restrict__ flagsA, const int* __restrict__ q,
                      const int* __restrict__ cbase, float* __restrict__ out){
    int blk = blockIdx.x, tid = threadIdx.x;
    int n = blk / NCHUNK, ch = blk % NCHUNK;
    int wave = tid >> 6, lane = tid & 63;
    int a = ch*256 + tid;
    int bs0 = q[n*4+0], bs1 = q[n*4+2];
    int f = flagsA[(long)n*A_TOT + a];
    int fg = (f>>5)&1;
    int bg = ((f>>6)&1) & !fg;
    int bin = (f>>7)&1023;
    int kept = 0;
    if(fg)      kept = (bin > bs0) || ((f & KEEPB) != 0);
    else if(bg) kept = (bin > bs1) || ((f & KEEPB) != 0);
    __shared__ int s_wc[4];
    unsigned long long mk = __ballot(kept);
    if(lane==0) s_wc[wave] = __popcll(mk);
    __syncthreads();
    if(kept){
        int base = cbase[n*NCHUNK + ch];
        for(int w=0; w<wave; ++w) base += s_wc[w];
        int slot = base + __popcll(mk & ((1ull<<lane)-1ull));
        if(slot < TOTAL_K){
            out[n*TOTAL_K + slot] = (float)a;
            out[(long)N_IMG*TOTAL_K + n*TOTAL_K + slot] = fg ? 1.0f : 0.0f;
            float4 aa = ((const float4*)anchors)[a];
            float4 gg = ((const float4*)gt)[n*M_GT + (f & 31)];
            float cf[4]; coeff_fn(aa, gg, cf);
            for(int k=0;k<4;++k)
                out[(long)2*N_IMG*TOTAL_K + ((long)n*TOTAL_K + slot)*4 + k] = cf[k];
        }
    }
}

extern "C" void kernel_launch(void* const* d_in, const int* in_sizes, int n_in,
                              void* d_out, int out_size, void* d_ws, size_t ws_size,
                              hipStream_t stream){
    const float* anchors = (const float*)d_in[0];  // [36864,4]
    const float* gt      = (const float*)d_in[1];  // [32,32,4]
    const float* dl      = (const float*)d_in[2];  // [32,36864,4]
    const float* rs      = (const float*)d_in[3];  // [32,36864]
    float* out = (float*)d_out;                    // idx[32,256] | fg[32,256] | coeff[32,256,4]
    char* ws = (char*)d_ws;
    size_t off = 0;
    int* flagsA   = (int*)(ws + off); off += (size_t)N_IMG*A_TOT*4;        // 4,718,592
    int* bmax     = (int*)(ws + off); off += (size_t)N_IMG*NCHUNK*M_GT*4;  // 589,824
    int* pgm      = (int*)(ws + off); off += 4096;                         // NOT zeroed (atomicMax over poison)
    int* hist     = (int*)(ws + off); off += (size_t)N_IMG*2048*4;         // 262,144 (memset)
    int* candcnt  = (int*)(ws + off); off += 256;                          // 64 ints (memset w/ hist)
    int* q        = (int*)(ws + off); off += 512;
    unsigned long long* cand = (unsigned long long*)(ws + off); off += (size_t)N_IMG*2*CAP*8;
    int* chunkcnt = (int*)(ws + off); off += (size_t)N_IMG*NCHUNK*4;
    int* cbase    = (int*)(ws + off); off += (size_t)N_IMG*NCHUNK*4;

    hipMemsetAsync(hist, 0, (size_t)N_IMG*2048*4 + 256, stream);   // hist | candcnt
    hipLaunchKernelGGL(k_main,  dim3(N_IMG*NCHUNK), dim3(256), 0, stream,
                       anchors, gt, dl, rs, bmax, flagsA, pgm, hist);
    hipLaunchKernelGGL(k_fix,   dim3(N_IMG*M_GT),   dim3(256), 0, stream,
                       anchors, gt, dl, bmax, pgm, flagsA, hist);
    hipLaunchKernelGGL(k_bound, dim3(N_IMG*NCHUNK), dim3(256), 0, stream,
                       flagsA, rs, hist, q, cand, candcnt, chunkcnt);
    hipLaunchKernelGGL(k_rank,  dim3(N_IMG),        dim3(256), 0, stream,
                       anchors, gt, flagsA, q, candcnt, cand, chunkcnt, cbase, out);
    hipLaunchKernelGGL(k_out,   dim3(N_IMG*NCHUNK), dim3(256), 0, stream,
                       anchors, gt, flagsA, q, cbase, out);
}